// Round 4
// baseline (541.870 us; speedup 1.0000x reference)
//
#include <hip/hip_runtime.h>

// ---------------------------------------------------------------------------
// CDiTBlock: complex DiT block on MI355X.
// R4: cgemm conflict-free LDS permutation (stage lane L -> row=L&15,chunk=L>>4
//     so frag reads are linear lane*16B); templated tiles TM x TN:
//     128x128 (QKV,f1: 64 MFMA / 16 ds_read per wave-iter), 64x64 (O,f2:
//     512 blocks = 2/CU). Double-buffered global_load_lds pipeline kept.
// ---------------------------------------------------------------------------

typedef unsigned short u16;
typedef unsigned int   u32;
typedef __attribute__((ext_vector_type(8))) __bf16 bf16x8;
typedef __attribute__((ext_vector_type(8))) u16    u16x8;
typedef __attribute__((ext_vector_type(4))) u16    u16x4;
typedef __attribute__((ext_vector_type(4))) float  f32x4;

#define MFMA16(a, b, c) __builtin_amdgcn_mfma_f32_16x16x32_bf16(a, b, c, 0, 0, 0)

static constexpr int Bd = 4, Td = 1024, Dd = 512, Hd = 8, DHd = 64, MLPd = 2048;

__device__ __forceinline__ u16 f2bf(float x) {
  unsigned int u = __builtin_bit_cast(unsigned int, x);
  u += 0x7fffu + ((u >> 16) & 1u);   // RNE
  return (u16)(u >> 16);
}
__device__ __forceinline__ bf16x8 ldsfrag(const u16* p) {
  return __builtin_bit_cast(bf16x8, *(const u16x8*)p);
}
__device__ __forceinline__ bf16x8 negbf(bf16x8 v) {
  u16x8 u = __builtin_bit_cast(u16x8, v);
  u ^= (u16)0x8000;
  return __builtin_bit_cast(bf16x8, u);
}
__device__ __forceinline__ float gelu_tanh(float x) {
  float t = tanhf(0.7978845608028654f * (x + 0.044715f * x * x * x));
  return 0.5f * x * (1.f + t);
}
// async global->LDS, 16B per lane, lds dest = base + lane*16 (wave-uniform base)
__device__ __forceinline__ void gload_lds16(const u16* g, u16* l) {
  __builtin_amdgcn_global_load_lds(
      (const __attribute__((address_space(1))) u32*)g,
      (__attribute__((address_space(3))) u32*)l, 16, 0, 0);
}

// ---------------- weight fp32 -> bf16 ----------------
struct CJobs {
  const float* src[12];
  u16* dst[12];
  int blk_start[13];
};
__global__ __launch_bounds__(256) void convert_kernel(CJobs J) {
  const int blk = blockIdx.x;
  int jj = 0;
  while (jj < 11 && blk >= J.blk_start[jj + 1]) ++jj;
  const int idx = (blk - J.blk_start[jj]) * 256 + threadIdx.x;
  const float4 v = ((const float4*)J.src[jj])[idx];
  u16x4 o;
  o[0] = f2bf(v.x); o[1] = f2bf(v.y); o[2] = f2bf(v.z); o[3] = f2bf(v.w);
  *(u16x4*)(J.dst[jj] + (size_t)idx * 4) = o;
}

// ---------------- ada: m = clinear(silu(c)) ----------------
__global__ __launch_bounds__(256) void ada_kernel(
    const float* __restrict__ c_re, const float* __restrict__ c_im,
    const float* __restrict__ Wr, const float* __restrict__ Wi,
    const float* __restrict__ br, const float* __restrict__ bi,
    float* __restrict__ m_r, float* __restrict__ m_i) {
  __shared__ __align__(16) float sr[512], si[512];
  const int b = blockIdx.x / 12, nb = blockIdx.x % 12;
  const int tid = threadIdx.x;
  for (int i = tid; i < 512; i += 256) {
    const float xr = c_re[b * 512 + i], xi = c_im[b * 512 + i];
    sr[i] = xr / (1.f + __expf(-xr));
    si[i] = xi / (1.f + __expf(-xi));
  }
  __syncthreads();
  const int n = nb * 256 + tid;
  const float4* wr4 = (const float4*)(Wr + (size_t)n * 512);
  const float4* wi4 = (const float4*)(Wi + (size_t)n * 512);
  const float4* sr4 = (const float4*)sr;
  const float4* si4 = (const float4*)si;
  float ar = 0.f, ai = 0.f;
  for (int k = 0; k < 128; ++k) {
    const float4 a_ = sr4[k], b_ = si4[k], u = wr4[k], v = wi4[k];
    ar += a_.x * u.x - b_.x * v.x + a_.y * u.y - b_.y * v.y +
          a_.z * u.z - b_.z * v.z + a_.w * u.w - b_.w * v.w;
    ai += b_.x * u.x + a_.x * v.x + b_.y * u.y + a_.y * v.y +
          b_.z * u.z + a_.z * v.z + b_.w * u.w + a_.w * v.w;
  }
  m_r[(size_t)b * 3072 + n] = ar + br[n] - bi[n];
  m_i[(size_t)b * 3072 + n] = ai + br[n] + bi[n];
}

// ---------------- LN + modulate -> bf16 ----------------
__global__ __launch_bounds__(256) void ln_mod_kernel(
    const float* __restrict__ xr, const float* __restrict__ xi,
    const float* __restrict__ mv_r, const float* __restrict__ mv_i,
    int off_sh, int off_sc,
    u16* __restrict__ hr, u16* __restrict__ hi) {
  const int row = blockIdx.x;          // b*1024 + t
  const int b = row >> 10;
  const int tid = threadIdx.x;
  const float* xrp = xr + (size_t)row * 512;
  const float* xip = xi + (size_t)row * 512;
  const float r0 = xrp[tid], r1 = xrp[tid + 256];
  const float i0 = xip[tid], i1 = xip[tid + 256];
  float s0 = r0 + r1, s1 = r0 * r0 + r1 * r1;
  float s2 = i0 + i1, s3 = i0 * i0 + i1 * i1;
  #pragma unroll
  for (int o = 32; o > 0; o >>= 1) {
    s0 += __shfl_down(s0, o); s1 += __shfl_down(s1, o);
    s2 += __shfl_down(s2, o); s3 += __shfl_down(s3, o);
  }
  __shared__ float red[4][4];
  if ((tid & 63) == 0) {
    const int wv = tid >> 6;
    red[wv][0] = s0; red[wv][1] = s1; red[wv][2] = s2; red[wv][3] = s3;
  }
  __syncthreads();
  s0 = red[0][0] + red[1][0] + red[2][0] + red[3][0];
  s1 = red[0][1] + red[1][1] + red[2][1] + red[3][1];
  s2 = red[0][2] + red[1][2] + red[2][2] + red[3][2];
  s3 = red[0][3] + red[1][3] + red[2][3] + red[3][3];
  const float mr = s0 * (1.f / 512.f), mi = s2 * (1.f / 512.f);
  const float vr = s1 * (1.f / 512.f) - mr * mr;
  const float vi = s3 * (1.f / 512.f) - mi * mi;
  const float rr = rsqrtf(vr + 1e-6f), ri = rsqrtf(vi + 1e-6f);
  const float* shr = mv_r + (size_t)b * 3072 + off_sh;
  const float* shi = mv_i + (size_t)b * 3072 + off_sh;
  const float* scr = mv_r + (size_t)b * 3072 + off_sc;
  const float* sci = mv_i + (size_t)b * 3072 + off_sc;
  #pragma unroll
  for (int jj = 0; jj < 2; ++jj) {
    const int n = tid + jj * 256;
    const float nr = ((jj ? r1 : r0) - mr) * rr;
    const float ni = ((jj ? i1 : i0) - mi) * ri;
    const float a = 1.f + scr[n], bb = sci[n];
    hr[(size_t)row * 512 + n] = f2bf(nr * a - ni * bb + shr[n]);
    hi[(size_t)row * 512 + n] = f2bf(nr * bb + ni * a + shi[n]);
  }
}

// ---------------- complex GEMM: out = A @ W^T (+bias, +epilogue) -----------
// TM x TN tile, BK=32; 4 waves 2x2 (wave: TM/2 x TN/2 output).
// Stage permutation: lane L fetches (row = L&15, kchunk = L>>4) so LDS slot L
// holds exactly what read-lane L of the MFMA frag wants -> ds_read is linear
// lane*16B: ZERO bank conflicts both directions. Double-buffered async
// global_load_lds; one vmcnt(0)+barrier per K-iter.
// EPI: 0=QKV (3 segs, bf16 out, seg0 scaled 0.125), 1=O-proj (gate+resid fp32)
//      2=f1 (gelu, bf16), 3=f2 (gate+resid -> d_out planes)
template <int TM, int TN, int EPI>
__global__ __launch_bounds__(256) void cgemm_kernel(
    const u16* __restrict__ Ar, const u16* __restrict__ Ai,
    const u16* __restrict__ W0r, const u16* __restrict__ W0i,
    const float* __restrict__ b0r, const float* __restrict__ b0i,
    const u16* __restrict__ W1r, const u16* __restrict__ W1i,
    const float* __restrict__ b1r, const float* __restrict__ b1i,
    const u16* __restrict__ W2r, const u16* __restrict__ W2i,
    const float* __restrict__ b2r, const float* __restrict__ b2i,
    int K, int ntiles_per_seg, int out_ld,
    u16* __restrict__ o0r, u16* __restrict__ o0i,
    u16* __restrict__ o1r, u16* __restrict__ o1i,
    u16* __restrict__ o2r, u16* __restrict__ o2i,
    const float* __restrict__ resid_r, const float* __restrict__ resid_i,
    const float* __restrict__ gate_r, const float* __restrict__ gate_i,
    float* __restrict__ ofr, float* __restrict__ ofi) {
  constexpr int MI = TM / 32;            // A frags per wave
  constexpr int NI = TN / 32;            // B frags per wave
  constexpr int ABLK = TM / 16;          // 1KB store blocks per A plane
  constexpr int BBLK = TN / 16;
  constexpr int NSTAGE = 2 * (ABLK + BBLK);
  const int seg = blockIdx.y / ntiles_per_seg;
  const int n0 = (blockIdx.y % ntiles_per_seg) * TN;
  const int m0 = blockIdx.x * TM;
  const u16* Wr = (seg == 0) ? W0r : (seg == 1) ? W1r : W2r;
  const u16* Wi = (seg == 0) ? W0i : (seg == 1) ? W1i : W2i;
  const float* br = (seg == 0) ? b0r : (seg == 1) ? b1r : b2r;
  const float* bi = (seg == 0) ? b0i : (seg == 1) ? b1i : b2i;
  u16* obr = (seg == 0) ? o0r : (seg == 1) ? o1r : o2r;
  u16* obi = (seg == 0) ? o0i : (seg == 1) ? o1i : o2i;

  __shared__ __align__(16) u16 sAr[2][TM * 32], sAi[2][TM * 32];
  __shared__ __align__(16) u16 sBr[2][TN * 32], sBi[2][TN * 32];

  const int tid = threadIdx.x;
  const int w = tid >> 6, lane = tid & 63;
  const int wm = w >> 1, wn = w & 1;
  const int q4 = lane >> 4, c = lane & 15;
  const int r16 = lane & 15, kc8 = (lane >> 4) * 8;  // conflict-free permutation

  auto stage = [&](int kt, int bs) {
    #pragma unroll
    for (int j = 0; j < NSTAGE / 4; ++j) {
      const int I = w + 4 * j;
      const u16* src;
      u16* dst;
      if (I < ABLK) {
        src = Ar + (size_t)(m0 + I * 16 + r16) * K + kt + kc8;
        dst = sAr[bs] + I * 512;
      } else if (I < 2 * ABLK) {
        const int s = I - ABLK;
        src = Ai + (size_t)(m0 + s * 16 + r16) * K + kt + kc8;
        dst = sAi[bs] + s * 512;
      } else if (I < 2 * ABLK + BBLK) {
        const int s = I - 2 * ABLK;
        src = Wr + (size_t)(n0 + s * 16 + r16) * K + kt + kc8;
        dst = sBr[bs] + s * 512;
      } else {
        const int s = I - 2 * ABLK - BBLK;
        src = Wi + (size_t)(n0 + s * 16 + r16) * K + kt + kc8;
        dst = sBi[bs] + s * 512;
      }
      gload_lds16(src, dst);
    }
  };

  const f32x4 z = {0.f, 0.f, 0.f, 0.f};
  f32x4 accR[MI][NI], accI[MI][NI];
  #pragma unroll
  for (int a = 0; a < MI; ++a)
    #pragma unroll
    for (int b2 = 0; b2 < NI; ++b2) { accR[a][b2] = z; accI[a][b2] = z; }

  stage(0, 0);
  asm volatile("s_waitcnt vmcnt(0)" ::: "memory");
  __syncthreads();
  int pb = 0;
  for (int kt = 0; kt < K; kt += 32) {
    if (kt + 32 < K) stage(kt + 32, pb ^ 1);   // async issue, overlaps compute
    bf16x8 a_r[MI], a_i[MI];
    #pragma unroll
    for (int mi = 0; mi < MI; ++mi) {
      const int blk = wm * MI + mi;
      a_r[mi] = ldsfrag(sAr[pb] + blk * 512 + lane * 8);
      a_i[mi] = ldsfrag(sAi[pb] + blk * 512 + lane * 8);
    }
    #pragma unroll
    for (int ni = 0; ni < NI; ++ni) {
      const int blk = wn * NI + ni;
      const bf16x8 b_r = ldsfrag(sBr[pb] + blk * 512 + lane * 8);
      const bf16x8 b_i = ldsfrag(sBi[pb] + blk * 512 + lane * 8);
      const bf16x8 b_n = negbf(b_i);
      #pragma unroll
      for (int mi = 0; mi < MI; ++mi) {
        accR[mi][ni] = MFMA16(a_r[mi], b_r, accR[mi][ni]);
        accR[mi][ni] = MFMA16(a_i[mi], b_n, accR[mi][ni]);
        accI[mi][ni] = MFMA16(a_i[mi], b_r, accI[mi][ni]);
        accI[mi][ni] = MFMA16(a_r[mi], b_i, accI[mi][ni]);
      }
    }
    asm volatile("s_waitcnt vmcnt(0)" ::: "memory");  // next tile landed
    __syncthreads();
    pb ^= 1;
  }

  const float scale = (EPI == 0 && seg == 0) ? 0.125f : 1.f;
  #pragma unroll
  for (int mi = 0; mi < MI; ++mi)
    #pragma unroll
    for (int ni = 0; ni < NI; ++ni) {
      const int n = n0 + wn * (TN / 2) + ni * 16 + c;
      const float biasr = br[n] - bi[n];
      const float biasi = br[n] + bi[n];
      #pragma unroll
      for (int r = 0; r < 4; ++r) {
        const int m = m0 + wm * (TM / 2) + mi * 16 + q4 * 4 + r;
        const float ore = accR[mi][ni][r] + biasr;
        const float oim = accI[mi][ni][r] + biasi;
        if (EPI == 0) {
          obr[(size_t)m * out_ld + n] = f2bf(ore * scale);
          obi[(size_t)m * out_ld + n] = f2bf(oim * scale);
        } else if (EPI == 2) {
          obr[(size_t)m * out_ld + n] = f2bf(gelu_tanh(ore));
          obi[(size_t)m * out_ld + n] = f2bf(gelu_tanh(oim));
        } else {  // 1 or 3: gate + residual, fp32 out
          const int bb = m >> 10;
          const float gr = gate_r[(size_t)bb * 3072 + n];
          const float gi = gate_i[(size_t)bb * 3072 + n];
          const size_t o = (size_t)m * 512 + n;
          ofr[o] = resid_r[o] + ore * gr - oim * gi;
          ofi[o] = resid_i[o] + ore * gi + oim * gr;
        }
      }
    }
}

// ---------------- V transpose: [b,t,(h,dh)] -> vT[(b,h),dh][t] ------------
// XOR-swizzled LDS tile: element (t,d) at u16 offset t*64 + ((d>>3)^(t>>3))*8
// + (d&7). Writes b128 conflict-optimal; gather reads 2-way (free).
__global__ __launch_bounds__(256) void vt_kernel(
    const u16* __restrict__ Vr, const u16* __restrict__ Vi,
    u16* __restrict__ vTr, u16* __restrict__ vTi) {
  __shared__ __align__(16) u16 tile[2][64 * 64];
  const int tid = threadIdx.x;
  const int tt = blockIdx.x, bh = blockIdx.y, b = bh >> 3, h = bh & 7;
  const size_t base = (size_t)b * Td * Dd + h * DHd;
  for (int idx = tid; idx < 512; idx += 256) {
    const int t = idx >> 3, dblk = idx & 7;
    const size_t g = base + (size_t)(tt * 64 + t) * Dd + dblk * 8;
    const int o = t * 64 + ((dblk ^ (t >> 3)) << 3);
    *(u16x8*)&tile[0][o] = *(const u16x8*)(Vr + g);
    *(u16x8*)&tile[1][o] = *(const u16x8*)(Vi + g);
  }
  __syncthreads();
  for (int idx = tid; idx < 512; idx += 256) {
    const int d = idx >> 3, cg = idx & 7;
    u16x8 o0, o1;
    #pragma unroll
    for (int j = 0; j < 8; ++j) {
      const int t = cg * 8 + j;
      const int o = t * 64 + (((d >> 3) ^ (t >> 3)) << 3) + (d & 7);
      o0[j] = tile[0][o];
      o1[j] = tile[1][o];
    }
    const size_t g = ((size_t)bh * 64 + d) * Td + tt * 64 + cg * 8;
    *(u16x8*)(vTr + g) = o0;
    *(u16x8*)(vTi + g) = o1;
  }
}

// ---------------- flash complex attention ----------------
// grid (T/64, B*H); block 256 (4 waves, 16 q-rows each). Q pre-scaled 0.125.
// sQV: Q in prologue, then V^T tiles. sK: K tiles, then P.
__global__ __launch_bounds__(256) void attn_kernel(
    const u16* __restrict__ Qr, const u16* __restrict__ Qi,
    const u16* __restrict__ Kr, const u16* __restrict__ Ki,
    const u16* __restrict__ vTr, const u16* __restrict__ vTi,
    u16* __restrict__ Or, u16* __restrict__ Oi) {
  __shared__ __align__(16) u16 sQV[2][64 * 72];
  __shared__ __align__(16) u16 sK[2][64 * 72];

  const int tid = threadIdx.x;
  const int w = tid >> 6, lane = tid & 63;
  const int q4 = lane >> 4, c = lane & 15;
  const int bh = blockIdx.y, b = bh >> 3, h = bh & 7;
  const int t0 = blockIdx.x * 64;
  const size_t base = (size_t)b * Td * Dd + h * DHd;
  const size_t vbase = (size_t)bh * 64 * Td;

  for (int idx = tid; idx < 512; idx += 256) {
    const int row = idx >> 3, cg = idx & 7;
    const size_t g = base + (size_t)(t0 + row) * Dd + cg * 8;
    const int lo = row * 72 + cg * 8;
    *(u16x8*)&sQV[0][lo] = *(const u16x8*)(Qr + g);
    *(u16x8*)&sQV[1][lo] = *(const u16x8*)(Qi + g);
  }
  __syncthreads();
  bf16x8 aQr[2], aQi[2], aQn[2];
  #pragma unroll
  for (int kc = 0; kc < 2; ++kc) {
    const int off = (w * 16 + c) * 72 + kc * 32 + q4 * 8;
    aQr[kc] = ldsfrag(&sQV[0][off]);
    aQi[kc] = ldsfrag(&sQV[1][off]);
    aQn[kc] = negbf(aQi[kc]);
  }
  __syncthreads();   // all waves hold Q frags; sQV now reusable for V^T

  float mst[2][4], lst[2][4];
  #pragma unroll
  for (int p = 0; p < 2; ++p)
    for (int r = 0; r < 4; ++r) { mst[p][r] = -1e30f; lst[p][r] = 0.f; }
  const f32x4 z = {0.f, 0.f, 0.f, 0.f};
  f32x4 U1[4], U2[4], U3[4], U4[4];
  for (int i = 0; i < 4; ++i) { U1[i] = z; U2[i] = z; U3[i] = z; U4[i] = z; }

  for (int kt = 0; kt < 16; ++kt) {
    for (int idx = tid; idx < 512; idx += 256) {
      const int row = idx >> 3, cg = idx & 7;
      const int lo = row * 72 + cg * 8;
      const size_t gk = base + (size_t)(kt * 64 + row) * Dd + cg * 8;
      *(u16x8*)&sK[0][lo] = *(const u16x8*)(Kr + gk);
      *(u16x8*)&sK[1][lo] = *(const u16x8*)(Ki + gk);
      const size_t gv = vbase + (size_t)row * Td + kt * 64 + cg * 8;
      *(u16x8*)&sQV[0][lo] = *(const u16x8*)(vTr + gv);
      *(u16x8*)&sQV[1][lo] = *(const u16x8*)(vTi + gv);
    }
    __syncthreads();

    f32x4 S[2][4];
    #pragma unroll
    for (int nb = 0; nb < 4; ++nb) {
      f32x4 tr = z, ti = z;
      #pragma unroll
      for (int kc = 0; kc < 2; ++kc) {
        const int off = (nb * 16 + c) * 72 + kc * 32 + q4 * 8;
        const bf16x8 bKr = ldsfrag(&sK[0][off]);
        const bf16x8 bKi = ldsfrag(&sK[1][off]);
        tr = MFMA16(aQr[kc], bKr, tr);
        tr = MFMA16(aQn[kc], bKi, tr);
        ti = MFMA16(aQi[kc], bKr, ti);
        ti = MFMA16(aQr[kc], bKi, ti);
      }
      S[0][nb] = tr; S[1][nb] = ti;
    }
    __syncthreads();  // all waves done reading K -> safe to overwrite with P

    float alpha[2][4];
    #pragma unroll
    for (int p = 0; p < 2; ++p) {
      float rs[4];
      #pragma unroll
      for (int r = 0; r < 4; ++r) {
        float tm = fmaxf(fmaxf(S[p][0][r], S[p][1][r]), fmaxf(S[p][2][r], S[p][3][r]));
        #pragma unroll
        for (int o = 1; o < 16; o <<= 1) tm = fmaxf(tm, __shfl_xor(tm, o));
        const float mn = fmaxf(mst[p][r], tm);
        alpha[p][r] = __expf(mst[p][r] - mn);
        mst[p][r] = mn;
        rs[r] = 0.f;
      }
      #pragma unroll
      for (int nb = 0; nb < 4; ++nb)
        #pragma unroll
        for (int r = 0; r < 4; ++r) {
          const float pv = __expf(S[p][nb][r] - mst[p][r]);
          rs[r] += pv;
          sK[p][(w * 16 + q4 * 4 + r) * 72 + nb * 16 + c] = f2bf(pv);
        }
      #pragma unroll
      for (int r = 0; r < 4; ++r) {
        float s = rs[r];
        #pragma unroll
        for (int o = 1; o < 16; o <<= 1) s += __shfl_xor(s, o);
        lst[p][r] = lst[p][r] * alpha[p][r] + s;
      }
    }
    #pragma unroll
    for (int i = 0; i < 4; ++i)
      #pragma unroll
      for (int r = 0; r < 4; ++r) {
        U1[i][r] *= alpha[0][r]; U2[i][r] *= alpha[0][r];
        U3[i][r] *= alpha[1][r]; U4[i][r] *= alpha[1][r];
      }
    asm volatile("s_waitcnt lgkmcnt(0)" ::: "memory");  // own-wave P RAW guard
    #pragma unroll
    for (int kc = 0; kc < 2; ++kc) {
      const int poff = (w * 16 + c) * 72 + kc * 32 + q4 * 8;
      const bf16x8 aPr = ldsfrag(&sK[0][poff]);
      const bf16x8 aPi = ldsfrag(&sK[1][poff]);
      #pragma unroll
      for (int nd = 0; nd < 4; ++nd) {
        const int voff = (nd * 16 + c) * 72 + kc * 32 + q4 * 8;
        const bf16x8 bVr = ldsfrag(&sQV[0][voff]);
        const bf16x8 bVi = ldsfrag(&sQV[1][voff]);
        U1[nd] = MFMA16(aPr, bVr, U1[nd]);
        U2[nd] = MFMA16(aPr, bVi, U2[nd]);
        U3[nd] = MFMA16(aPi, bVr, U3[nd]);
        U4[nd] = MFMA16(aPi, bVi, U4[nd]);
      }
    }
    __syncthreads();
  }

  #pragma unroll
  for (int nd = 0; nd < 4; ++nd)
    #pragma unroll
    for (int r = 0; r < 4; ++r) {
      const int trow = t0 + w * 16 + q4 * 4 + r;
      const int d = nd * 16 + c;
      const float ilre = 1.f / lst[0][r], ilim = 1.f / lst[1][r];
      const float ore = U1[nd][r] * ilre - U4[nd][r] * ilim;
      const float oim = U2[nd][r] * ilre + U3[nd][r] * ilim;
      const size_t g = base + (size_t)trow * Dd + d;
      Or[g] = f2bf(ore);
      Oi[g] = f2bf(oim);
    }
}

// ---------------------------------------------------------------------------
extern "C" void kernel_launch(void* const* d_in, const int* in_sizes, int n_in,
                              void* d_out, int out_size, void* d_ws, size_t ws_size,
                              hipStream_t stream) {
  const float* x_re  = (const float*)d_in[0];
  const float* x_im  = (const float*)d_in[1];
  const float* c_re  = (const float*)d_in[2];
  const float* c_im  = (const float*)d_in[3];
  const float* adaWr = (const float*)d_in[4];
  const float* adaWi = (const float*)d_in[5];
  const float* adabr = (const float*)d_in[6];
  const float* adabi = (const float*)d_in[7];
  const float* qWr = (const float*)d_in[8],  *qWi = (const float*)d_in[9];
  const float* qbr = (const float*)d_in[10], *qbi = (const float*)d_in[11];
  const float* kWr = (const float*)d_in[12], *kWi = (const float*)d_in[13];
  const float* kbr = (const float*)d_in[14], *kbi = (const float*)d_in[15];
  const float* vWr = (const float*)d_in[16], *vWi = (const float*)d_in[17];
  const float* vbr = (const float*)d_in[18], *vbi = (const float*)d_in[19];
  const float* oWr = (const float*)d_in[20], *oWi = (const float*)d_in[21];
  const float* obr = (const float*)d_in[22], *obi = (const float*)d_in[23];
  const float* f1Wr = (const float*)d_in[24], *f1Wi = (const float*)d_in[25];
  const float* f1br = (const float*)d_in[26], *f1bi = (const float*)d_in[27];
  const float* f2Wr = (const float*)d_in[28], *f2Wi = (const float*)d_in[29];
  const float* f2br = (const float*)d_in[30], *f2bi = (const float*)d_in[31];

  char* wsp = (char*)d_ws;
  size_t off = 0;
  auto alloc = [&](size_t bytes) -> void* {
    void* p = wsp + off;
    off += (bytes + 255) & ~(size_t)255;
    return p;
  };
  const size_t WQ = 512 * 512, WF = 2048 * 512;   // elements
  u16* wqr = (u16*)alloc(WQ * 2); u16* wqi = (u16*)alloc(WQ * 2);
  u16* wkr = (u16*)alloc(WQ * 2); u16* wki = (u16*)alloc(WQ * 2);
  u16* wvr = (u16*)alloc(WQ * 2); u16* wvi = (u16*)alloc(WQ * 2);
  u16* wor = (u16*)alloc(WQ * 2); u16* woi = (u16*)alloc(WQ * 2);
  u16* wf1r = (u16*)alloc(WF * 2); u16* wf1i = (u16*)alloc(WF * 2);
  u16* wf2r = (u16*)alloc(WF * 2); u16* wf2i = (u16*)alloc(WF * 2);
  float* m_r = (float*)alloc(4 * 3072 * 4);
  float* m_i = (float*)alloc(4 * 3072 * 4);
  const size_t ACT = (size_t)Bd * Td * Dd;        // 2,097,152 elements
  u16* h1r = (u16*)alloc(ACT * 2); u16* h1i = (u16*)alloc(ACT * 2);
  u16* qbr_ = (u16*)alloc(ACT * 2); u16* qbi_ = (u16*)alloc(ACT * 2);
  u16* kbr_ = (u16*)alloc(ACT * 2); u16* kbi_ = (u16*)alloc(ACT * 2);
  u16* vbr_ = (u16*)alloc(ACT * 2); u16* vbi_ = (u16*)alloc(ACT * 2);
  u16* atr = (u16*)alloc(ACT * 2); u16* ati = (u16*)alloc(ACT * 2);
  float* x2r = (float*)alloc(ACT * 4); float* x2i = (float*)alloc(ACT * 4);
  u16* vtr = (u16*)alloc(ACT * 2); u16* vti = (u16*)alloc(ACT * 2);
  // aliases (dead buffers reused)
  u16* h2r = h1r; u16* h2i = h1i;                 // h1 dead after QKV
  u16* f1or = qbr_;                               // q..attn (32MB) dead after O-proj
  u16* f1oi = qbr_ + (size_t)Bd * Td * MLPd;

  // 1) weights -> bf16
  CJobs J;
  const float* wsrc[12] = {qWr, qWi, kWr, kWi, vWr, vWi, oWr, oWi, f1Wr, f1Wi, f2Wr, f2Wi};
  u16* wdst[12] = {wqr, wqi, wkr, wki, wvr, wvi, wor, woi, wf1r, wf1i, wf2r, wf2i};
  int cum = 0;
  for (int j = 0; j < 12; ++j) {
    J.src[j] = wsrc[j]; J.dst[j] = wdst[j]; J.blk_start[j] = cum;
    cum += (j < 8 ? (int)WQ : (int)WF) / 1024;
  }
  J.blk_start[12] = cum;  // 6144
  convert_kernel<<<cum, 256, 0, stream>>>(J);

  // 2) ada modulation vectors
  ada_kernel<<<48, 256, 0, stream>>>(c_re, c_im, adaWr, adaWi, adabr, adabi, m_r, m_i);

  // 3) LN1 + modulate(sh_a, sc_a)
  ln_mod_kernel<<<4096, 256, 0, stream>>>(x_re, x_im, m_r, m_i, 0, 512, h1r, h1i);

  // 4) QKV (q scaled by 1/sqrt(DH)=0.125 in epilogue)
  cgemm_kernel<128, 128, 0><<<dim3(32, 12), 256, 0, stream>>>(
      h1r, h1i, wqr, wqi, qbr, qbi, wkr, wki, kbr, kbi, wvr, wvi, vbr, vbi,
      512, 4, 512, qbr_, qbi_, kbr_, kbi_, vbr_, vbi_,
      nullptr, nullptr, nullptr, nullptr, nullptr, nullptr);

  // 4b) V -> V^T (per (b,h): [dh][t])
  vt_kernel<<<dim3(16, 32), 256, 0, stream>>>(vbr_, vbi_, vtr, vti);

  // 5) attention
  attn_kernel<<<dim3(16, 32), 256, 0, stream>>>(qbr_, qbi_, kbr_, kbi_, vtr, vti, atr, ati);

  // 6) O-proj + gate_a + residual -> x2 (fp32)
  cgemm_kernel<64, 64, 1><<<dim3(64, 8), 256, 0, stream>>>(
      atr, ati, wor, woi, obr, obi, wor, woi, obr, obi, wor, woi, obr, obi,
      512, 8, 512, nullptr, nullptr, nullptr, nullptr, nullptr, nullptr,
      x_re, x_im, m_r + 1024, m_i + 1024, x2r, x2i);

  // 7) LN2 + modulate(sh_m, sc_m)
  ln_mod_kernel<<<4096, 256, 0, stream>>>(x2r, x2i, m_r, m_i, 1536, 2048, h2r, h2i);

  // 8) f1 + gelu
  cgemm_kernel<128, 128, 2><<<dim3(32, 16), 256, 0, stream>>>(
      h2r, h2i, wf1r, wf1i, f1br, f1bi, wf1r, wf1i, f1br, f1bi, wf1r, wf1i, f1br, f1bi,
      512, 16, 2048, f1or, f1oi, nullptr, nullptr, nullptr, nullptr,
      nullptr, nullptr, nullptr, nullptr, nullptr, nullptr);

  // 9) f2 + gate_m + residual -> d_out (2 planes)
  float* outp = (float*)d_out;
  cgemm_kernel<64, 64, 3><<<dim3(64, 8), 256, 0, stream>>>(
      f1or, f1oi, wf2r, wf2i, f2br, f2bi, wf2r, wf2i, f2br, f2bi, wf2r, wf2i, f2br, f2bi,
      2048, 8, 512, nullptr, nullptr, nullptr, nullptr, nullptr, nullptr,
      x2r, x2i, m_r + 2560, m_i + 2560, outp, outp + ACT);
}

// Round 5
// 502.543 us; speedup vs baseline: 1.0783x; 1.0783x over previous
//
#include <hip/hip_runtime.h>

// ---------------------------------------------------------------------------
// CDiTBlock: complex DiT block on MI355X.
// R5: cgemm rebuilt as m97-replica: single-buffer, 2-barrier K-loop, BK=32,
//     conflict-free stage permutation, small wave tiles (32x32, acc 32 regs)
//     with __launch_bounds__(NT,6) -> 3 blocks/CU co-residency (m114 overlap).
//     QKV/f1: 512-thr TM=128/TN=64 (24KB LDS). O: 256-thr 64x64. f2: split-K=2
//     (grid.z) -> fp32 partials + fuse kernel (sum+bias+gate+resid).
// ---------------------------------------------------------------------------

typedef unsigned short u16;
typedef unsigned int   u32;
typedef __attribute__((ext_vector_type(8))) __bf16 bf16x8;
typedef __attribute__((ext_vector_type(8))) u16    u16x8;
typedef __attribute__((ext_vector_type(4))) u16    u16x4;
typedef __attribute__((ext_vector_type(4))) float  f32x4;

#define MFMA16(a, b, c) __builtin_amdgcn_mfma_f32_16x16x32_bf16(a, b, c, 0, 0, 0)

static constexpr int Bd = 4, Td = 1024, Dd = 512, Hd = 8, DHd = 64, MLPd = 2048;
static constexpr size_t ACTe = (size_t)Bd * Td * Dd;   // 2,097,152

__device__ __forceinline__ u16 f2bf(float x) {
  unsigned int u = __builtin_bit_cast(unsigned int, x);
  u += 0x7fffu + ((u >> 16) & 1u);   // RNE
  return (u16)(u >> 16);
}
__device__ __forceinline__ bf16x8 ldsfrag(const u16* p) {
  return __builtin_bit_cast(bf16x8, *(const u16x8*)p);
}
__device__ __forceinline__ bf16x8 negbf(bf16x8 v) {
  u16x8 u = __builtin_bit_cast(u16x8, v);
  u ^= (u16)0x8000;
  return __builtin_bit_cast(bf16x8, u);
}
__device__ __forceinline__ float gelu_tanh(float x) {
  float t = tanhf(0.7978845608028654f * (x + 0.044715f * x * x * x));
  return 0.5f * x * (1.f + t);
}
__device__ __forceinline__ void gload_lds16(const u16* g, u16* l) {
  __builtin_amdgcn_global_load_lds(
      (const __attribute__((address_space(1))) u32*)g,
      (__attribute__((address_space(3))) u32*)l, 16, 0, 0);
}

// ---------------- weight fp32 -> bf16 ----------------
struct CJobs {
  const float* src[12];
  u16* dst[12];
  int blk_start[13];
};
__global__ __launch_bounds__(256) void convert_kernel(CJobs J) {
  const int blk = blockIdx.x;
  int jj = 0;
  while (jj < 11 && blk >= J.blk_start[jj + 1]) ++jj;
  const int idx = (blk - J.blk_start[jj]) * 256 + threadIdx.x;
  const float4 v = ((const float4*)J.src[jj])[idx];
  u16x4 o;
  o[0] = f2bf(v.x); o[1] = f2bf(v.y); o[2] = f2bf(v.z); o[3] = f2bf(v.w);
  *(u16x4*)(J.dst[jj] + (size_t)idx * 4) = o;
}

// ---------------- ada: m = clinear(silu(c)) ----------------
__global__ __launch_bounds__(256) void ada_kernel(
    const float* __restrict__ c_re, const float* __restrict__ c_im,
    const float* __restrict__ Wr, const float* __restrict__ Wi,
    const float* __restrict__ br, const float* __restrict__ bi,
    float* __restrict__ m_r, float* __restrict__ m_i) {
  __shared__ __align__(16) float sr[512], si[512];
  const int b = blockIdx.x / 12, nb = blockIdx.x % 12;
  const int tid = threadIdx.x;
  for (int i = tid; i < 512; i += 256) {
    const float xr = c_re[b * 512 + i], xi = c_im[b * 512 + i];
    sr[i] = xr / (1.f + __expf(-xr));
    si[i] = xi / (1.f + __expf(-xi));
  }
  __syncthreads();
  const int n = nb * 256 + tid;
  const float4* wr4 = (const float4*)(Wr + (size_t)n * 512);
  const float4* wi4 = (const float4*)(Wi + (size_t)n * 512);
  const float4* sr4 = (const float4*)sr;
  const float4* si4 = (const float4*)si;
  float ar = 0.f, ai = 0.f;
  for (int k = 0; k < 128; ++k) {
    const float4 a_ = sr4[k], b_ = si4[k], u = wr4[k], v = wi4[k];
    ar += a_.x * u.x - b_.x * v.x + a_.y * u.y - b_.y * v.y +
          a_.z * u.z - b_.z * v.z + a_.w * u.w - b_.w * v.w;
    ai += b_.x * u.x + a_.x * v.x + b_.y * u.y + a_.y * v.y +
          b_.z * u.z + a_.z * v.z + b_.w * u.w + a_.w * v.w;
  }
  m_r[(size_t)b * 3072 + n] = ar + br[n] - bi[n];
  m_i[(size_t)b * 3072 + n] = ai + br[n] + bi[n];
}

// ---------------- LN + modulate -> bf16 ----------------
__global__ __launch_bounds__(256) void ln_mod_kernel(
    const float* __restrict__ xr, const float* __restrict__ xi,
    const float* __restrict__ mv_r, const float* __restrict__ mv_i,
    int off_sh, int off_sc,
    u16* __restrict__ hr, u16* __restrict__ hi) {
  const int row = blockIdx.x;          // b*1024 + t
  const int b = row >> 10;
  const int tid = threadIdx.x;
  const float* xrp = xr + (size_t)row * 512;
  const float* xip = xi + (size_t)row * 512;
  const float r0 = xrp[tid], r1 = xrp[tid + 256];
  const float i0 = xip[tid], i1 = xip[tid + 256];
  float s0 = r0 + r1, s1 = r0 * r0 + r1 * r1;
  float s2 = i0 + i1, s3 = i0 * i0 + i1 * i1;
  #pragma unroll
  for (int o = 32; o > 0; o >>= 1) {
    s0 += __shfl_down(s0, o); s1 += __shfl_down(s1, o);
    s2 += __shfl_down(s2, o); s3 += __shfl_down(s3, o);
  }
  __shared__ float red[4][4];
  if ((tid & 63) == 0) {
    const int wv = tid >> 6;
    red[wv][0] = s0; red[wv][1] = s1; red[wv][2] = s2; red[wv][3] = s3;
  }
  __syncthreads();
  s0 = red[0][0] + red[1][0] + red[2][0] + red[3][0];
  s1 = red[0][1] + red[1][1] + red[2][1] + red[3][1];
  s2 = red[0][2] + red[1][2] + red[2][2] + red[3][2];
  s3 = red[0][3] + red[1][3] + red[2][3] + red[3][3];
  const float mr = s0 * (1.f / 512.f), mi = s2 * (1.f / 512.f);
  const float vr = s1 * (1.f / 512.f) - mr * mr;
  const float vi = s3 * (1.f / 512.f) - mi * mi;
  const float rr = rsqrtf(vr + 1e-6f), ri = rsqrtf(vi + 1e-6f);
  const float* shr = mv_r + (size_t)b * 3072 + off_sh;
  const float* shi = mv_i + (size_t)b * 3072 + off_sh;
  const float* scr = mv_r + (size_t)b * 3072 + off_sc;
  const float* sci = mv_i + (size_t)b * 3072 + off_sc;
  #pragma unroll
  for (int jj = 0; jj < 2; ++jj) {
    const int n = tid + jj * 256;
    const float nr = ((jj ? r1 : r0) - mr) * rr;
    const float ni = ((jj ? i1 : i0) - mi) * ri;
    const float a = 1.f + scr[n], bb = sci[n];
    hr[(size_t)row * 512 + n] = f2bf(nr * a - ni * bb + shr[n]);
    hi[(size_t)row * 512 + n] = f2bf(nr * bb + ni * a + shi[n]);
  }
}

// ---------------- complex GEMM (m97 structure) -----------------------------
// NT=512: TM=128 (8 waves 4x2), NT=256: TM=64 (4 waves 2x2). TN=64, BK=32.
// Wave tile 32x32: 16 MFMA : 8 ds_read_b128 : NSTAGE/NW gloads per iter.
// Single LDS buffer (24/16 KB), stage->vmcnt+bar->compute->bar.
// Stage permutation lane L -> (row L&15, kchunk L>>4): frag read = lane*16B,
// zero bank conflicts. min-waves 6 -> 3 blocks/CU (512-thr) by VGPR<=85.
// EPI: 0=QKV (3 segs, bf16, seg0 *0.125)  1=O-proj (gate+resid fp32)
//      2=f1 (gelu bf16)  4=split-K raw fp32 partial (blockIdx.z = K-half)
template <int NT, int EPI>
__global__ __launch_bounds__(NT, 6) void cgemm_kernel(
    const u16* __restrict__ Ar, const u16* __restrict__ Ai,
    const u16* __restrict__ W0r, const u16* __restrict__ W0i,
    const float* __restrict__ b0r, const float* __restrict__ b0i,
    const u16* __restrict__ W1r, const u16* __restrict__ W1i,
    const float* __restrict__ b1r, const float* __restrict__ b1i,
    const u16* __restrict__ W2r, const u16* __restrict__ W2i,
    const float* __restrict__ b2r, const float* __restrict__ b2i,
    int Klen, int ldk, int ntiles_per_seg, int out_ld,
    u16* __restrict__ o0r, u16* __restrict__ o0i,
    u16* __restrict__ o1r, u16* __restrict__ o1i,
    u16* __restrict__ o2r, u16* __restrict__ o2i,
    const float* __restrict__ resid_r, const float* __restrict__ resid_i,
    const float* __restrict__ gate_r, const float* __restrict__ gate_i,
    float* __restrict__ ofr, float* __restrict__ ofi) {
  constexpr int TM = (NT == 512) ? 128 : 64;
  constexpr int TN = 64;
  constexpr int NW = NT / 64;
  constexpr int ABLK = TM / 16, BBLK = TN / 16;
  constexpr int NSTAGE = 2 * (ABLK + BBLK);
  const int seg = blockIdx.y / ntiles_per_seg;
  const int n0 = (blockIdx.y % ntiles_per_seg) * TN;
  const int m0 = blockIdx.x * TM;
  const int kz = (EPI == 4) ? blockIdx.z : 0;
  const int kbase = kz * Klen;
  const u16* Wr = (seg == 0) ? W0r : (seg == 1) ? W1r : W2r;
  const u16* Wi = (seg == 0) ? W0i : (seg == 1) ? W1i : W2i;
  const float* br = (seg == 0) ? b0r : (seg == 1) ? b1r : b2r;
  const float* bi = (seg == 0) ? b0i : (seg == 1) ? b1i : b2i;
  u16* obr = (seg == 0) ? o0r : (seg == 1) ? o1r : o2r;
  u16* obi = (seg == 0) ? o0i : (seg == 1) ? o1i : o2i;

  __shared__ __align__(16) u16 sAr[TM * 32], sAi[TM * 32];
  __shared__ __align__(16) u16 sBr[TN * 32], sBi[TN * 32];

  const int tid = threadIdx.x;
  const int w = tid >> 6, lane = tid & 63;
  const int wm = w >> 1, wn = w & 1;
  const int q4 = lane >> 4, c = lane & 15;
  const int r16 = lane & 15, kc8 = (lane >> 4) * 8;  // conflict-free perm

  const f32x4 z = {0.f, 0.f, 0.f, 0.f};
  f32x4 accR[2][2], accI[2][2];
  #pragma unroll
  for (int a = 0; a < 2; ++a)
    #pragma unroll
    for (int b2 = 0; b2 < 2; ++b2) { accR[a][b2] = z; accI[a][b2] = z; }

  for (int kt = 0; kt < Klen; kt += 32) {
    // ---- stage tile (single buffer) ----
    #pragma unroll
    for (int j = 0; j < NSTAGE / NW; ++j) {
      const int I = w + NW * j;
      const u16* src;
      u16* dst;
      if (I < ABLK) {
        src = Ar + (size_t)(m0 + I * 16 + r16) * ldk + kbase + kt + kc8;
        dst = sAr + I * 512;
      } else if (I < 2 * ABLK) {
        const int s = I - ABLK;
        src = Ai + (size_t)(m0 + s * 16 + r16) * ldk + kbase + kt + kc8;
        dst = sAi + s * 512;
      } else if (I < 2 * ABLK + BBLK) {
        const int s = I - 2 * ABLK;
        src = Wr + (size_t)(n0 + s * 16 + r16) * ldk + kbase + kt + kc8;
        dst = sBr + s * 512;
      } else {
        const int s = I - 2 * ABLK - BBLK;
        src = Wi + (size_t)(n0 + s * 16 + r16) * ldk + kbase + kt + kc8;
        dst = sBi + s * 512;
      }
      gload_lds16(src, dst);
    }
    asm volatile("s_waitcnt vmcnt(0)" ::: "memory");
    __syncthreads();
    // ---- compute ----
    bf16x8 a_r[2], a_i[2];
    #pragma unroll
    for (int mi = 0; mi < 2; ++mi) {
      a_r[mi] = ldsfrag(sAr + (wm * 2 + mi) * 512 + lane * 8);
      a_i[mi] = ldsfrag(sAi + (wm * 2 + mi) * 512 + lane * 8);
    }
    #pragma unroll
    for (int ni = 0; ni < 2; ++ni) {
      const bf16x8 b_r = ldsfrag(sBr + (wn * 2 + ni) * 512 + lane * 8);
      const bf16x8 b_i = ldsfrag(sBi + (wn * 2 + ni) * 512 + lane * 8);
      const bf16x8 b_n = negbf(b_i);
      #pragma unroll
      for (int mi = 0; mi < 2; ++mi) {
        accR[mi][ni] = MFMA16(a_r[mi], b_r, accR[mi][ni]);
        accR[mi][ni] = MFMA16(a_i[mi], b_n, accR[mi][ni]);
        accI[mi][ni] = MFMA16(a_i[mi], b_r, accI[mi][ni]);
        accI[mi][ni] = MFMA16(a_r[mi], b_i, accI[mi][ni]);
      }
    }
    __syncthreads();   // all waves done reading before next stage overwrites
  }

  const float scale = (EPI == 0 && seg == 0) ? 0.125f : 1.f;
  #pragma unroll
  for (int mi = 0; mi < 2; ++mi)
    #pragma unroll
    for (int ni = 0; ni < 2; ++ni) {
      const int n = n0 + wn * 32 + ni * 16 + c;
      const float biasr = (EPI == 4) ? 0.f : br[n] - bi[n];
      const float biasi = (EPI == 4) ? 0.f : br[n] + bi[n];
      #pragma unroll
      for (int r = 0; r < 4; ++r) {
        const int m = m0 + wm * 32 + mi * 16 + q4 * 4 + r;
        const float ore = accR[mi][ni][r] + biasr;
        const float oim = accI[mi][ni][r] + biasi;
        if (EPI == 0) {
          obr[(size_t)m * out_ld + n] = f2bf(ore * scale);
          obi[(size_t)m * out_ld + n] = f2bf(oim * scale);
        } else if (EPI == 2) {
          obr[(size_t)m * out_ld + n] = f2bf(gelu_tanh(ore));
          obi[(size_t)m * out_ld + n] = f2bf(gelu_tanh(oim));
        } else if (EPI == 4) {
          const size_t o = (size_t)kz * 4096 * out_ld + (size_t)m * out_ld + n;
          ofr[o] = ore;
          ofi[o] = oim;
        } else {  // 1: gate + residual, fp32 out
          const int bb = m >> 10;
          const float gr = gate_r[(size_t)bb * 3072 + n];
          const float gi = gate_i[(size_t)bb * 3072 + n];
          const size_t o = (size_t)m * 512 + n;
          ofr[o] = resid_r[o] + ore * gr - oim * gi;
          ofi[o] = resid_i[o] + ore * gi + oim * gr;
        }
      }
    }
}

// ---------------- f2 fuse: sum split-K partials + bias + gate + resid ------
__global__ __launch_bounds__(256) void f2fuse_kernel(
    const float* __restrict__ p_r, const float* __restrict__ p_i,  // [2][ACT]
    const float* __restrict__ br, const float* __restrict__ bi,
    const float* __restrict__ gate_r, const float* __restrict__ gate_i,
    const float* __restrict__ x2r, const float* __restrict__ x2i,
    float* __restrict__ outr, float* __restrict__ outi) {
  const size_t e = ((size_t)blockIdx.x * 256 + threadIdx.x) * 4;
  const int n = (int)(e & 511);
  const int m = (int)(e >> 9);
  const int b = m >> 10;
  const float4 a0 = *(const float4*)(p_r + e);
  const float4 a1 = *(const float4*)(p_r + ACTe + e);
  const float4 c0 = *(const float4*)(p_i + e);
  const float4 c1 = *(const float4*)(p_i + ACTe + e);
  const float4 vbr = *(const float4*)(br + n);
  const float4 vbi = *(const float4*)(bi + n);
  const float4 vgr = *(const float4*)(gate_r + (size_t)b * 3072 + n);
  const float4 vgi = *(const float4*)(gate_i + (size_t)b * 3072 + n);
  const float4 xr = *(const float4*)(x2r + e);
  const float4 xi = *(const float4*)(x2i + e);
  float4 orr, oii;
  {
    const float pr[4] = {a0.x + a1.x, a0.y + a1.y, a0.z + a1.z, a0.w + a1.w};
    const float pi[4] = {c0.x + c1.x, c0.y + c1.y, c0.z + c1.z, c0.w + c1.w};
    const float brr[4] = {vbr.x, vbr.y, vbr.z, vbr.w};
    const float bii[4] = {vbi.x, vbi.y, vbi.z, vbi.w};
    const float gr[4] = {vgr.x, vgr.y, vgr.z, vgr.w};
    const float gi[4] = {vgi.x, vgi.y, vgi.z, vgi.w};
    const float xrr[4] = {xr.x, xr.y, xr.z, xr.w};
    const float xii[4] = {xi.x, xi.y, xi.z, xi.w};
    float outr4[4], outi4[4];
    #pragma unroll
    for (int j = 0; j < 4; ++j) {
      const float ore = pr[j] + brr[j] - bii[j];
      const float oim = pi[j] + brr[j] + bii[j];
      outr4[j] = xrr[j] + ore * gr[j] - oim * gi[j];
      outi4[j] = xii[j] + ore * gi[j] + oim * gr[j];
    }
    orr = {outr4[0], outr4[1], outr4[2], outr4[3]};
    oii = {outi4[0], outi4[1], outi4[2], outi4[3]};
  }
  *(float4*)(outr + e) = orr;
  *(float4*)(outi + e) = oii;
}

// ---------------- V transpose: [b,t,(h,dh)] -> vT[(b,h),dh][t] ------------
__global__ __launch_bounds__(256) void vt_kernel(
    const u16* __restrict__ Vr, const u16* __restrict__ Vi,
    u16* __restrict__ vTr, u16* __restrict__ vTi) {
  __shared__ __align__(16) u16 tile[2][64 * 64];
  const int tid = threadIdx.x;
  const int tt = blockIdx.x, bh = blockIdx.y, b = bh >> 3, h = bh & 7;
  const size_t base = (size_t)b * Td * Dd + h * DHd;
  for (int idx = tid; idx < 512; idx += 256) {
    const int t = idx >> 3, dblk = idx & 7;
    const size_t g = base + (size_t)(tt * 64 + t) * Dd + dblk * 8;
    const int o = t * 64 + ((dblk ^ (t >> 3)) << 3);
    *(u16x8*)&tile[0][o] = *(const u16x8*)(Vr + g);
    *(u16x8*)&tile[1][o] = *(const u16x8*)(Vi + g);
  }
  __syncthreads();
  for (int idx = tid; idx < 512; idx += 256) {
    const int d = idx >> 3, cg = idx & 7;
    u16x8 o0, o1;
    #pragma unroll
    for (int j = 0; j < 8; ++j) {
      const int t = cg * 8 + j;
      const int o = t * 64 + (((d >> 3) ^ (t >> 3)) << 3) + (d & 7);
      o0[j] = tile[0][o];
      o1[j] = tile[1][o];
    }
    const size_t g = ((size_t)bh * 64 + d) * Td + tt * 64 + cg * 8;
    *(u16x8*)(vTr + g) = o0;
    *(u16x8*)(vTi + g) = o1;
  }
}

// ---------------- flash complex attention ----------------
__global__ __launch_bounds__(256) void attn_kernel(
    const u16* __restrict__ Qr, const u16* __restrict__ Qi,
    const u16* __restrict__ Kr, const u16* __restrict__ Ki,
    const u16* __restrict__ vTr, const u16* __restrict__ vTi,
    u16* __restrict__ Or, u16* __restrict__ Oi) {
  __shared__ __align__(16) u16 sQV[2][64 * 72];
  __shared__ __align__(16) u16 sK[2][64 * 72];

  const int tid = threadIdx.x;
  const int w = tid >> 6, lane = tid & 63;
  const int q4 = lane >> 4, c = lane & 15;
  const int bh = blockIdx.y, b = bh >> 3, h = bh & 7;
  const int t0 = blockIdx.x * 64;
  const size_t base = (size_t)b * Td * Dd + h * DHd;
  const size_t vbase = (size_t)bh * 64 * Td;

  for (int idx = tid; idx < 512; idx += 256) {
    const int row = idx >> 3, cg = idx & 7;
    const size_t g = base + (size_t)(t0 + row) * Dd + cg * 8;
    const int lo = row * 72 + cg * 8;
    *(u16x8*)&sQV[0][lo] = *(const u16x8*)(Qr + g);
    *(u16x8*)&sQV[1][lo] = *(const u16x8*)(Qi + g);
  }
  __syncthreads();
  bf16x8 aQr[2], aQi[2], aQn[2];
  #pragma unroll
  for (int kc = 0; kc < 2; ++kc) {
    const int off = (w * 16 + c) * 72 + kc * 32 + q4 * 8;
    aQr[kc] = ldsfrag(&sQV[0][off]);
    aQi[kc] = ldsfrag(&sQV[1][off]);
    aQn[kc] = negbf(aQi[kc]);
  }
  __syncthreads();   // sQV now reusable for V^T

  float mst[2][4], lst[2][4];
  #pragma unroll
  for (int p = 0; p < 2; ++p)
    for (int r = 0; r < 4; ++r) { mst[p][r] = -1e30f; lst[p][r] = 0.f; }
  const f32x4 z = {0.f, 0.f, 0.f, 0.f};
  f32x4 U1[4], U2[4], U3[4], U4[4];
  for (int i = 0; i < 4; ++i) { U1[i] = z; U2[i] = z; U3[i] = z; U4[i] = z; }

  for (int kt = 0; kt < 16; ++kt) {
    for (int idx = tid; idx < 512; idx += 256) {
      const int row = idx >> 3, cg = idx & 7;
      const int lo = row * 72 + cg * 8;
      const size_t gk = base + (size_t)(kt * 64 + row) * Dd + cg * 8;
      *(u16x8*)&sK[0][lo] = *(const u16x8*)(Kr + gk);
      *(u16x8*)&sK[1][lo] = *(const u16x8*)(Ki + gk);
      const size_t gv = vbase + (size_t)row * Td + kt * 64 + cg * 8;
      *(u16x8*)&sQV[0][lo] = *(const u16x8*)(vTr + gv);
      *(u16x8*)&sQV[1][lo] = *(const u16x8*)(vTi + gv);
    }
    __syncthreads();

    f32x4 S[2][4];
    #pragma unroll
    for (int nb = 0; nb < 4; ++nb) {
      f32x4 tr = z, ti = z;
      #pragma unroll
      for (int kc = 0; kc < 2; ++kc) {
        const int off = (nb * 16 + c) * 72 + kc * 32 + q4 * 8;
        const bf16x8 bKr = ldsfrag(&sK[0][off]);
        const bf16x8 bKi = ldsfrag(&sK[1][off]);
        tr = MFMA16(aQr[kc], bKr, tr);
        tr = MFMA16(aQn[kc], bKi, tr);
        ti = MFMA16(aQi[kc], bKr, ti);
        ti = MFMA16(aQr[kc], bKi, ti);
      }
      S[0][nb] = tr; S[1][nb] = ti;
    }
    __syncthreads();  // safe to overwrite sK with P

    float alpha[2][4];
    #pragma unroll
    for (int p = 0; p < 2; ++p) {
      float rs[4];
      #pragma unroll
      for (int r = 0; r < 4; ++r) {
        float tm = fmaxf(fmaxf(S[p][0][r], S[p][1][r]), fmaxf(S[p][2][r], S[p][3][r]));
        #pragma unroll
        for (int o = 1; o < 16; o <<= 1) tm = fmaxf(tm, __shfl_xor(tm, o));
        const float mn = fmaxf(mst[p][r], tm);
        alpha[p][r] = __expf(mst[p][r] - mn);
        mst[p][r] = mn;
        rs[r] = 0.f;
      }
      #pragma unroll
      for (int nb = 0; nb < 4; ++nb)
        #pragma unroll
        for (int r = 0; r < 4; ++r) {
          const float pv = __expf(S[p][nb][r] - mst[p][r]);
          rs[r] += pv;
          sK[p][(w * 16 + q4 * 4 + r) * 72 + nb * 16 + c] = f2bf(pv);
        }
      #pragma unroll
      for (int r = 0; r < 4; ++r) {
        float s = rs[r];
        #pragma unroll
        for (int o = 1; o < 16; o <<= 1) s += __shfl_xor(s, o);
        lst[p][r] = lst[p][r] * alpha[p][r] + s;
      }
    }
    #pragma unroll
    for (int i = 0; i < 4; ++i)
      #pragma unroll
      for (int r = 0; r < 4; ++r) {
        U1[i][r] *= alpha[0][r]; U2[i][r] *= alpha[0][r];
        U3[i][r] *= alpha[1][r]; U4[i][r] *= alpha[1][r];
      }
    asm volatile("s_waitcnt lgkmcnt(0)" ::: "memory");  // own-wave P RAW guard
    #pragma unroll
    for (int kc = 0; kc < 2; ++kc) {
      const int poff = (w * 16 + c) * 72 + kc * 32 + q4 * 8;
      const bf16x8 aPr = ldsfrag(&sK[0][poff]);
      const bf16x8 aPi = ldsfrag(&sK[1][poff]);
      #pragma unroll
      for (int nd = 0; nd < 4; ++nd) {
        const int voff = (nd * 16 + c) * 72 + kc * 32 + q4 * 8;
        const bf16x8 bVr = ldsfrag(&sQV[0][voff]);
        const bf16x8 bVi = ldsfrag(&sQV[1][voff]);
        U1[nd] = MFMA16(aPr, bVr, U1[nd]);
        U2[nd] = MFMA16(aPr, bVi, U2[nd]);
        U3[nd] = MFMA16(aPi, bVr, U3[nd]);
        U4[nd] = MFMA16(aPi, bVi, U4[nd]);
      }
    }
    __syncthreads();
  }

  #pragma unroll
  for (int nd = 0; nd < 4; ++nd)
    #pragma unroll
    for (int r = 0; r < 4; ++r) {
      const int trow = t0 + w * 16 + q4 * 4 + r;
      const int d = nd * 16 + c;
      const float ilre = 1.f / lst[0][r], ilim = 1.f / lst[1][r];
      const float ore = U1[nd][r] * ilre - U4[nd][r] * ilim;
      const float oim = U2[nd][r] * ilre + U3[nd][r] * ilim;
      const size_t g = base + (size_t)trow * Dd + d;
      Or[g] = f2bf(ore);
      Oi[g] = f2bf(oim);
    }
}

// ---------------------------------------------------------------------------
extern "C" void kernel_launch(void* const* d_in, const int* in_sizes, int n_in,
                              void* d_out, int out_size, void* d_ws, size_t ws_size,
                              hipStream_t stream) {
  const float* x_re  = (const float*)d_in[0];
  const float* x_im  = (const float*)d_in[1];
  const float* c_re  = (const float*)d_in[2];
  const float* c_im  = (const float*)d_in[3];
  const float* adaWr = (const float*)d_in[4];
  const float* adaWi = (const float*)d_in[5];
  const float* adabr = (const float*)d_in[6];
  const float* adabi = (const float*)d_in[7];
  const float* qWr = (const float*)d_in[8],  *qWi = (const float*)d_in[9];
  const float* qbr = (const float*)d_in[10], *qbi = (const float*)d_in[11];
  const float* kWr = (const float*)d_in[12], *kWi = (const float*)d_in[13];
  const float* kbr = (const float*)d_in[14], *kbi = (const float*)d_in[15];
  const float* vWr = (const float*)d_in[16], *vWi = (const float*)d_in[17];
  const float* vbr = (const float*)d_in[18], *vbi = (const float*)d_in[19];
  const float* oWr = (const float*)d_in[20], *oWi = (const float*)d_in[21];
  const float* obr = (const float*)d_in[22], *obi = (const float*)d_in[23];
  const float* f1Wr = (const float*)d_in[24], *f1Wi = (const float*)d_in[25];
  const float* f1br = (const float*)d_in[26], *f1bi = (const float*)d_in[27];
  const float* f2Wr = (const float*)d_in[28], *f2Wi = (const float*)d_in[29];
  const float* f2br = (const float*)d_in[30], *f2bi = (const float*)d_in[31];

  char* wsp = (char*)d_ws;
  size_t off = 0;
  auto alloc = [&](size_t bytes) -> void* {
    void* p = wsp + off;
    off += (bytes + 255) & ~(size_t)255;
    return p;
  };
  const size_t WQ = 512 * 512, WF = 2048 * 512;   // elements
  u16* wqr = (u16*)alloc(WQ * 2); u16* wqi = (u16*)alloc(WQ * 2);
  u16* wkr = (u16*)alloc(WQ * 2); u16* wki = (u16*)alloc(WQ * 2);
  u16* wvr = (u16*)alloc(WQ * 2); u16* wvi = (u16*)alloc(WQ * 2);
  u16* wor = (u16*)alloc(WQ * 2); u16* woi = (u16*)alloc(WQ * 2);
  u16* wf1r = (u16*)alloc(WF * 2); u16* wf1i = (u16*)alloc(WF * 2);
  u16* wf2r = (u16*)alloc(WF * 2); u16* wf2i = (u16*)alloc(WF * 2);
  float* m_r = (float*)alloc(4 * 3072 * 4);
  float* m_i = (float*)alloc(4 * 3072 * 4);
  const size_t ACT = ACTe;                        // 2,097,152 elements
  u16* h1r = (u16*)alloc(ACT * 2); u16* h1i = (u16*)alloc(ACT * 2);
  u16* qbr_ = (u16*)alloc(ACT * 2); u16* qbi_ = (u16*)alloc(ACT * 2);
  u16* kbr_ = (u16*)alloc(ACT * 2); u16* kbi_ = (u16*)alloc(ACT * 2);
  u16* vbr_ = (u16*)alloc(ACT * 2); u16* vbi_ = (u16*)alloc(ACT * 2);
  u16* atr = (u16*)alloc(ACT * 2); u16* ati = (u16*)alloc(ACT * 2);
  float* x2r = (float*)alloc(ACT * 4); float* x2i = (float*)alloc(ACT * 4);
  u16* vtr = (u16*)alloc(ACT * 2); u16* vti = (u16*)alloc(ACT * 2);
  float* p_r = (float*)alloc(2 * ACT * 4);        // f2 split-K partials re
  float* p_i = (float*)alloc(2 * ACT * 4);        // f2 split-K partials im
  // aliases (dead buffers reused)
  u16* h2r = h1r; u16* h2i = h1i;                 // h1 dead after QKV
  u16* f1or = qbr_;                               // q..attn dead after O-proj
  u16* f1oi = qbr_ + (size_t)Bd * Td * MLPd;

  // 1) weights -> bf16
  CJobs J;
  const float* wsrc[12] = {qWr, qWi, kWr, kWi, vWr, vWi, oWr, oWi, f1Wr, f1Wi, f2Wr, f2Wi};
  u16* wdst[12] = {wqr, wqi, wkr, wki, wvr, wvi, wor, woi, wf1r, wf1i, wf2r, wf2i};
  int cum = 0;
  for (int j = 0; j < 12; ++j) {
    J.src[j] = wsrc[j]; J.dst[j] = wdst[j]; J.blk_start[j] = cum;
    cum += (j < 8 ? (int)WQ : (int)WF) / 1024;
  }
  J.blk_start[12] = cum;  // 6144
  convert_kernel<<<cum, 256, 0, stream>>>(J);

  // 2) ada modulation vectors
  ada_kernel<<<48, 256, 0, stream>>>(c_re, c_im, adaWr, adaWi, adabr, adabi, m_r, m_i);

  // 3) LN1 + modulate(sh_a, sc_a)
  ln_mod_kernel<<<4096, 256, 0, stream>>>(x_re, x_im, m_r, m_i, 0, 512, h1r, h1i);

  // 4) QKV (q scaled 0.125): 512-thr, TM=128, grid (32, 3*8) = 768 blocks
  cgemm_kernel<512, 0><<<dim3(32, 24), 512, 0, stream>>>(
      h1r, h1i, wqr, wqi, qbr, qbi, wkr, wki, kbr, kbi, wvr, wvi, vbr, vbi,
      512, 512, 8, 512, qbr_, qbi_, kbr_, kbi_, vbr_, vbi_,
      nullptr, nullptr, nullptr, nullptr, nullptr, nullptr);

  // 4b) V -> V^T
  vt_kernel<<<dim3(16, 32), 256, 0, stream>>>(vbr_, vbi_, vtr, vti);

  // 5) attention
  attn_kernel<<<dim3(16, 32), 256, 0, stream>>>(qbr_, qbi_, kbr_, kbi_, vtr, vti, atr, ati);

  // 6) O-proj + gate_a + residual -> x2 (fp32): 256-thr, 512 blocks
  cgemm_kernel<256, 1><<<dim3(64, 8), 256, 0, stream>>>(
      atr, ati, wor, woi, obr, obi, wor, woi, obr, obi, wor, woi, obr, obi,
      512, 512, 8, 512, nullptr, nullptr, nullptr, nullptr, nullptr, nullptr,
      x_re, x_im, m_r + 1024, m_i + 1024, x2r, x2i);

  // 7) LN2 + modulate(sh_m, sc_m)
  ln_mod_kernel<<<4096, 256, 0, stream>>>(x2r, x2i, m_r, m_i, 1536, 2048, h2r, h2i);

  // 8) f1 + gelu: 512-thr, grid (32, 32) = 1024 blocks
  cgemm_kernel<512, 2><<<dim3(32, 32), 512, 0, stream>>>(
      h2r, h2i, wf1r, wf1i, f1br, f1bi, wf1r, wf1i, f1br, f1bi, wf1r, wf1i, f1br, f1bi,
      512, 512, 32, 2048, f1or, f1oi, nullptr, nullptr, nullptr, nullptr,
      nullptr, nullptr, nullptr, nullptr, nullptr, nullptr);

  // 9) f2 split-K=2: raw partials, grid (64, 8, 2) = 1024 blocks
  cgemm_kernel<256, 4><<<dim3(64, 8, 2), 256, 0, stream>>>(
      f1or, f1oi, wf2r, wf2i, f2br, f2bi, wf2r, wf2i, f2br, f2bi, wf2r, wf2i, f2br, f2bi,
      1024, 2048, 8, 512, nullptr, nullptr, nullptr, nullptr, nullptr, nullptr,
      nullptr, nullptr, nullptr, nullptr, p_r, p_i);

  // 10) fuse: sum partials + bias + gate_m + residual -> d_out
  float* outp = (float*)d_out;
  f2fuse_kernel<<<(int)(ACT / 4 / 256), 256, 0, stream>>>(
      p_r, p_i, f2br, f2bi, m_r + 2560, m_i + 2560, x2r, x2i, outp, outp + ACT);
}